// Round 9
// baseline (190.109 us; speedup 1.0000x reference)
//
#include <hip/hip_runtime.h>

constexpr int   N_NODES = 102400;      // B * NODES_PER_GRAPH
constexpr int   F_IN    = 400;
constexpr int   HIDF    = 4;
constexpr int   B_GR    = 256;
constexpr int   NPG     = 400;         // nodes per graph
constexpr int   E_EDGES = 6553600;

// two-level sort parameters
constexpr int   NBK     = 512;                 // buckets (dst/200)
constexpr int   NPB2    = 200;                 // nodes per bucket
constexpr int   GB      = 800;                 // binning blocks
constexpr int   CHUNK   = E_EDGES / GB;        // 8192 edges per block
constexpr int   HITERS  = CHUNK / 256;         // 32 (hist part of k_xw_hist)
constexpr int   CNT     = NBK * GB;            // 409600 counters
constexpr int   SCANB   = CNT / 1024;          // 400 scan blocks
constexpr int   CAP2    = 14336;               // bucket staging (mean 12800, +13 sigma)
constexpr float FPSCALE = 16777216.0f;         // 2^24 fixed-point for degree

// ---------------- fused: hist blocks first, then xw (independent) ----------------
__global__ __launch_bounds__(256) void k_xw_hist(const float* __restrict__ x,
                                                 const float* __restrict__ W,
                                                 const int* __restrict__ ei,
                                                 float* __restrict__ h,
                                                 unsigned* __restrict__ counts) {
    if (blockIdx.x < GB) {
        __shared__ unsigned hist[NBK];
        for (int i = threadIdx.x; i < NBK; i += 256) hist[i] = 0;
        __syncthreads();
        long long base = (long long)blockIdx.x * CHUNK;
        #pragma unroll 4
        for (int i = 0; i < HITERS; ++i) {
            int d = ei[E_EDGES + base + i * 256 + threadIdx.x];
            atomicAdd(&hist[d / NPB2], 1u);
        }
        __syncthreads();
        for (int i = threadIdx.x; i < NBK; i += 256)
            counts[(unsigned)i * GB + blockIdx.x] = hist[i];
        return;
    }
    int gtid = (blockIdx.x - GB) * 256 + threadIdx.x;
    int row  = gtid >> 6;
    int lane = threadIdx.x & 63;
    if (row >= N_NODES) return;
    const float* xr = x + (long long)row * F_IN;
    float a0 = 0.f, a1 = 0.f, a2 = 0.f, a3 = 0.f;
    for (int k0 = lane * 4; k0 < F_IN; k0 += 256) {
        float4 xv = *reinterpret_cast<const float4*>(xr + k0);
        float4 w0 = *reinterpret_cast<const float4*>(W + (k0 + 0) * 4);
        float4 w1 = *reinterpret_cast<const float4*>(W + (k0 + 1) * 4);
        float4 w2 = *reinterpret_cast<const float4*>(W + (k0 + 2) * 4);
        float4 w3 = *reinterpret_cast<const float4*>(W + (k0 + 3) * 4);
        a0 = fmaf(xv.x, w0.x, a0); a1 = fmaf(xv.x, w0.y, a1); a2 = fmaf(xv.x, w0.z, a2); a3 = fmaf(xv.x, w0.w, a3);
        a0 = fmaf(xv.y, w1.x, a0); a1 = fmaf(xv.y, w1.y, a1); a2 = fmaf(xv.y, w1.z, a2); a3 = fmaf(xv.y, w1.w, a3);
        a0 = fmaf(xv.z, w2.x, a0); a1 = fmaf(xv.z, w2.y, a1); a2 = fmaf(xv.z, w2.z, a2); a3 = fmaf(xv.z, w2.w, a3);
        a0 = fmaf(xv.w, w3.x, a0); a1 = fmaf(xv.w, w3.y, a1); a2 = fmaf(xv.w, w3.z, a2); a3 = fmaf(xv.w, w3.w, a3);
    }
    for (int off = 32; off; off >>= 1) {
        a0 += __shfl_down(a0, off, 64);
        a1 += __shfl_down(a1, off, 64);
        a2 += __shfl_down(a2, off, 64);
        a3 += __shfl_down(a3, off, 64);
    }
    if (lane == 0) {
        float4 r = make_float4(a0, a1, a2, a3);
        *reinterpret_cast<float4*>(h + (long long)row * 4) = r;
    }
}

// ---------------- scan1: per-1024-chunk exclusive scan ----------------
__global__ __launch_bounds__(256) void k_scan1(unsigned* __restrict__ data,
                                               unsigned* __restrict__ bsum) {
    __shared__ unsigned ts[256];
    int base = blockIdx.x * 1024 + threadIdx.x * 4;
    unsigned v0 = data[base], v1 = data[base + 1], v2 = data[base + 2], v3 = data[base + 3];
    unsigned s = v0 + v1 + v2 + v3;
    ts[threadIdx.x] = s;
    __syncthreads();
    for (int off = 1; off < 256; off <<= 1) {
        unsigned t = (threadIdx.x >= off) ? ts[threadIdx.x - off] : 0u;
        __syncthreads();
        ts[threadIdx.x] += t;
        __syncthreads();
    }
    unsigned excl = ts[threadIdx.x] - s;
    data[base]     = excl;
    data[base + 1] = excl + v0;
    data[base + 2] = excl + v0 + v1;
    data[base + 3] = excl + v0 + v1 + v2;
    if (threadIdx.x == 255) bsum[blockIdx.x] = ts[255];
}

// ---------------- scan2: exclusive scan of the SCANB chunk sums ----------------
__global__ __launch_bounds__(512) void k_scan2(unsigned* __restrict__ bsum) {
    __shared__ unsigned ts[512];
    int tid = threadIdx.x;
    unsigned v = (tid < SCANB) ? bsum[tid] : 0u;
    ts[tid] = v;
    __syncthreads();
    for (int off = 1; off < 512; off <<= 1) {
        unsigned t = (tid >= off) ? ts[tid - off] : 0u;
        __syncthreads();
        ts[tid] += t;
        __syncthreads();
    }
    if (tid < SCANB) bsum[tid] = ts[tid] - v;   // exclusive
}

// helper: global exclusive prefix at flat index (after scan1+scan2)
__device__ __forceinline__ unsigned pfx(const unsigned* counts, const unsigned* bsum,
                                        unsigned flat) {
    return (flat < (unsigned)CNT) ? (counts[flat] + bsum[flat >> 10]) : (unsigned)E_EDGES;
}

// ---------------- binsort v4: single edge pass (hist from scanned-count diff) ----------------
__global__ __launch_bounds__(1024) void k_binsort(const int* __restrict__ ei,
                                                  const float* __restrict__ ew,
                                                  const unsigned* __restrict__ counts,
                                                  const unsigned* __restrict__ bsum,
                                                  unsigned long long* __restrict__ sorted) {
    __shared__ unsigned long long st2[CHUNK];   // 64 KB, bucket-ordered staging
    __shared__ unsigned hist[NBK], lrank[NBK], lobase[NBK], obaseG[NBK];
    __shared__ unsigned wsum[8];
    int tid = threadIdx.x;
    unsigned v = 0, inc = 0;
    if (tid < NBK) {
        unsigned flat = (unsigned)tid * GB + blockIdx.x;
        unsigned o0 = pfx(counts, bsum, flat);
        unsigned o1 = pfx(counts, bsum, flat + 1);
        obaseG[tid] = o0;
        v = o1 - o0;                // this block's count for this bucket
        hist[tid] = v;
        lrank[tid] = 0;
        inc = v;
        #pragma unroll
        for (int d = 1; d < 64; d <<= 1) {
            unsigned t = __shfl_up(inc, d, 64);
            if ((tid & 63) >= d) inc += t;
        }
        if ((tid & 63) == 63) wsum[tid >> 6] = inc;
    }
    __syncthreads();
    if (tid < 8) {
        unsigned s = wsum[tid], si = s;
        #pragma unroll
        for (int d = 1; d < 8; d <<= 1) {
            unsigned t = __shfl_up(si, d, 64);
            if (tid >= d) si += t;
        }
        wsum[tid] = si - s;
    }
    __syncthreads();
    if (tid < NBK) lobase[tid] = inc - v + wsum[tid >> 6];
    __syncthreads();
    // single pass: read edges, permute into st2 (bucket-ordered in LDS)
    long long base = (long long)blockIdx.x * CHUNK;
    #pragma unroll
    for (int k = 0; k < CHUNK / 1024; ++k) {
        long long e = base + k * 1024 + tid;
        int   sv = ei[e];
        int   dv = ei[E_EDGES + e];
        float wv = ew[e];
        int bin  = dv / NPB2;
        int dloc = dv - bin * NPB2;
        unsigned r = atomicAdd(&lrank[bin], 1u);
        st2[lobase[bin] + r] = ((unsigned long long)__float_as_uint(wv) << 32)
                             | ((unsigned)sv << 9) | (unsigned)dloc;
    }
    __syncthreads();
    // run write-out, 16-lane subgroup per bucket
    int sg = tid >> 4, l = tid & 15;
    for (int bin = sg; bin < NBK; bin += 64) {
        unsigned cnt = hist[bin];
        unsigned gb  = obaseG[bin];
        unsigned lb  = lobase[bin];
        for (unsigned k = l; k < cnt; k += 16)
            sorted[gb + k] = st2[lb + k];
    }
}

// ---------------- sort2 v4: fixed-point weighted degree -> dinv, hs (no sorting at all) ----------------
__global__ __launch_bounds__(1024) void k_sort2(const unsigned* __restrict__ counts,
                                                const unsigned* __restrict__ bsum,
                                                const unsigned long long* __restrict__ sa,
                                                const float* __restrict__ h,
                                                float* __restrict__ dinv,
                                                float* __restrict__ hs) {
    __shared__ unsigned dgu[NPB2];
    int tid = threadIdx.x;
    int b = blockIdx.x;
    unsigned s0 = pfx(counts, bsum, (unsigned)b * GB);
    unsigned s1 = pfx(counts, bsum, (unsigned)(b + 1) * GB);
    unsigned len = s1 - s0;
    if (tid < NPB2) dgu[tid] = 0;
    __syncthreads();
    // accumulate w (fixed-point u32: native LDS atomic, no f32-atomic wall)
    unsigned i = tid;
    for (; i + 3 * 1024 < len; i += 4 * 1024) {
        unsigned long long p0 = sa[s0 + i];
        unsigned long long p1 = sa[s0 + i + 1024];
        unsigned long long p2 = sa[s0 + i + 2048];
        unsigned long long p3 = sa[s0 + i + 3072];
        atomicAdd(&dgu[(unsigned)p0 & 511u], __float2uint_rn(__uint_as_float((unsigned)(p0 >> 32)) * FPSCALE));
        atomicAdd(&dgu[(unsigned)p1 & 511u], __float2uint_rn(__uint_as_float((unsigned)(p1 >> 32)) * FPSCALE));
        atomicAdd(&dgu[(unsigned)p2 & 511u], __float2uint_rn(__uint_as_float((unsigned)(p2 >> 32)) * FPSCALE));
        atomicAdd(&dgu[(unsigned)p3 & 511u], __float2uint_rn(__uint_as_float((unsigned)(p3 >> 32)) * FPSCALE));
    }
    for (; i < len; i += 1024) {
        unsigned long long pk = sa[s0 + i];
        atomicAdd(&dgu[(unsigned)pk & 511u], __float2uint_rn(__uint_as_float((unsigned)(pk >> 32)) * FPSCALE));
    }
    __syncthreads();
    if (tid < NPB2 * 4) {
        int node = tid >> 2, c = tid & 3;
        float deg = 1.0f + (float)dgu[node] * (1.0f / FPSCALE);   // self-loop weight 1
        float di = rsqrtf(deg);
        int gnode = b * NPB2 + node;
        if (c == 0) dinv[gnode] = di;
        hs[gnode * 4 + c] = di * h[gnode * 4 + c];
    }
}

// ---------------- gather v5: dl16+idx in LDS, edge records via L2 ----------------
__global__ __launch_bounds__(1024) void k_gather(const unsigned* __restrict__ counts,
                                                 const unsigned* __restrict__ bsum,
                                                 const unsigned long long* __restrict__ sa,
                                                 const float* __restrict__ hs,
                                                 const float* __restrict__ dinv,
                                                 const float* __restrict__ bias,
                                                 float* __restrict__ feat) {
    __shared__ unsigned short dl16[CAP2];       // 28,672 B
    __shared__ unsigned short idx[CAP2];        // 28,672 B
    __shared__ unsigned hist[NPB2], rnk[NPB2], obase[NPB2];
    __shared__ unsigned wsum[4];
    __shared__ float accf[4 * NPB2];            // overflow fallback only
    int tid = threadIdx.x;
    int b = blockIdx.x;
    unsigned s0 = pfx(counts, bsum, (unsigned)b * GB);
    unsigned s1 = pfx(counts, bsum, (unsigned)(b + 1) * GB);
    unsigned len = s1 - s0;
    bool staged = (len <= (unsigned)CAP2);
    if (tid < NPB2) { hist[tid] = 0; rnk[tid] = 0; }
    __syncthreads();
    if (staged) {
        // pass 1: dloc -> LDS, histogram
        for (unsigned i = tid; i < len; i += 1024) {
            unsigned dl = (unsigned)sa[s0 + i] & 511u;
            dl16[i] = (unsigned short)dl;
            atomicAdd(&hist[dl], 1u);
        }
        __syncthreads();
        // exclusive scan of hist[200] via wave shuffles
        unsigned v = 0, inc = 0;
        if (tid < 256) {
            v = (tid < NPB2) ? hist[tid] : 0u;
            inc = v;
            #pragma unroll
            for (int d = 1; d < 64; d <<= 1) {
                unsigned t = __shfl_up(inc, d, 64);
                if ((tid & 63) >= d) inc += t;
            }
            if ((tid & 63) == 63) wsum[tid >> 6] = inc;
        }
        __syncthreads();
        if (tid < 4) {
            unsigned s = wsum[tid], si = s;
            #pragma unroll
            for (int d = 1; d < 4; d <<= 1) {
                unsigned t = __shfl_up(si, d, 64);
                if (tid >= d) si += t;
            }
            wsum[tid] = si - s;
        }
        __syncthreads();
        if (tid < NPB2) obase[tid] = inc - v + wsum[tid >> 6];
        __syncthreads();
        // pass 2: inverse permutation (LDS only)
        for (unsigned i = tid; i < len; i += 1024) {
            unsigned dl = dl16[i];
            unsigned r = atomicAdd(&rnk[dl], 1u);
            idx[obase[dl] + r] = (unsigned short)i;
        }
        __syncthreads();
        // pass 3: per-node accumulate; edge records re-read via idx (segment L2-hot)
        if (tid < NPB2 * 4) {
            int node = tid >> 2, c = tid & 3;
            unsigned jst = obase[node];
            unsigned jen = (node < NPB2 - 1) ? obase[node + 1] : len;
            float acc = 0.f;
            unsigned j = jst;
            for (; j + 4 <= jen; j += 4) {
                unsigned long long p0 = sa[s0 + idx[j]];
                unsigned long long p1 = sa[s0 + idx[j + 1]];
                unsigned long long p2 = sa[s0 + idx[j + 2]];
                unsigned long long p3 = sa[s0 + idx[j + 3]];
                float h0 = hs[(((unsigned)p0 >> 9) << 2) + c];
                float h1 = hs[(((unsigned)p1 >> 9) << 2) + c];
                float h2 = hs[(((unsigned)p2 >> 9) << 2) + c];
                float h3 = hs[(((unsigned)p3 >> 9) << 2) + c];
                acc = fmaf(__uint_as_float((unsigned)(p0 >> 32)), h0, acc);
                acc = fmaf(__uint_as_float((unsigned)(p1 >> 32)), h1, acc);
                acc = fmaf(__uint_as_float((unsigned)(p2 >> 32)), h2, acc);
                acc = fmaf(__uint_as_float((unsigned)(p3 >> 32)), h3, acc);
            }
            for (; j < jen; ++j) {
                unsigned long long pk = sa[s0 + idx[j]];
                acc = fmaf(__uint_as_float((unsigned)(pk >> 32)),
                           hs[(((unsigned)pk >> 9) << 2) + c], acc);
            }
            int gnode = b * NPB2 + node;
            feat[gnode * 4 + c] = fmaf(dinv[gnode], acc + hs[gnode * 4 + c], bias[c]);
        }
    } else {
        // overflow fallback (statistically never): f32 LDS atomics
        for (int i = tid; i < 4 * NPB2; i += 1024) accf[i] = 0.f;
        __syncthreads();
        for (unsigned i = tid; i < len; i += 1024) {
            unsigned long long pk = sa[s0 + i];
            unsigned lo = (unsigned)pk;
            float w = __uint_as_float((unsigned)(pk >> 32));
            int dl = lo & 511;
            const float* hv = hs + (((unsigned)lo >> 9) << 2);
            atomicAdd(&accf[dl * 4 + 0], w * hv[0]);
            atomicAdd(&accf[dl * 4 + 1], w * hv[1]);
            atomicAdd(&accf[dl * 4 + 2], w * hv[2]);
            atomicAdd(&accf[dl * 4 + 3], w * hv[3]);
        }
        __syncthreads();
        if (tid < NPB2 * 4) {
            int node = tid >> 2, c = tid & 3;
            int gnode = b * NPB2 + node;
            feat[gnode * 4 + c] = fmaf(dinv[gnode], accf[node * 4 + c] + hs[gnode * 4 + c], bias[c]);
        }
    }
}

// ---------------- mlp: per-graph FC head ----------------
__global__ __launch_bounds__(256) void k_mlp(const float* __restrict__ feat,
                                             const float* __restrict__ fc1w,
                                             const float* __restrict__ fc1b,
                                             const float* __restrict__ fc2w,
                                             const float* __restrict__ fc2b,
                                             float* __restrict__ out) {
    __shared__ float row[NPG * HIDF];
    __shared__ float part[8][32];
    __shared__ float h1[32];
    int g = blockIdx.x;
    const float* fr = feat + (long long)g * (NPG * HIDF);
    for (int i = threadIdx.x; i < NPG * HIDF; i += 256) row[i] = fr[i];
    __syncthreads();
    int j = threadIdx.x & 31;
    int c8 = threadIdx.x >> 5;
    float acc = 0.f;
    int k0 = c8 * 200, k1 = k0 + 200;
    for (int k = k0; k < k1; ++k) acc = fmaf(row[k], fc1w[k * 32 + j], acc);
    part[c8][j] = acc;
    __syncthreads();
    if (threadIdx.x < 32) {
        float s = fc1b[j];
        #pragma unroll
        for (int cc = 0; cc < 8; ++cc) s += part[cc][j];
        h1[j] = fmaxf(s, 0.f);
    }
    __syncthreads();
    if (threadIdx.x < 2) {
        float s = fc2b[threadIdx.x];
        #pragma unroll
        for (int k = 0; k < 32; ++k) s = fmaf(h1[k], fc2w[k * 2 + threadIdx.x], s);
        out[g * 2 + threadIdx.x] = s;
    }
    if (g == 0 && threadIdx.x == 0) out[B_GR * 2] = 0.0f;
}

// ---------------- fallback path (global atomics, ~5.3 MB ws) ----------------
__global__ __launch_bounds__(256) void k_xwf(const float* __restrict__ x,
                                             const float* __restrict__ W,
                                             float* __restrict__ h) {
    int gtid = blockIdx.x * 256 + threadIdx.x;
    int row  = gtid >> 6;
    int lane = threadIdx.x & 63;
    if (row >= N_NODES) return;
    const float* xr = x + (long long)row * F_IN;
    float a0 = 0.f, a1 = 0.f, a2 = 0.f, a3 = 0.f;
    for (int k0 = lane * 4; k0 < F_IN; k0 += 256) {
        float4 xv = *reinterpret_cast<const float4*>(xr + k0);
        float4 w0 = *reinterpret_cast<const float4*>(W + (k0 + 0) * 4);
        float4 w1 = *reinterpret_cast<const float4*>(W + (k0 + 1) * 4);
        float4 w2 = *reinterpret_cast<const float4*>(W + (k0 + 2) * 4);
        float4 w3 = *reinterpret_cast<const float4*>(W + (k0 + 3) * 4);
        a0 = fmaf(xv.x, w0.x, a0); a1 = fmaf(xv.x, w0.y, a1); a2 = fmaf(xv.x, w0.z, a2); a3 = fmaf(xv.x, w0.w, a3);
        a0 = fmaf(xv.y, w1.x, a0); a1 = fmaf(xv.y, w1.y, a1); a2 = fmaf(xv.y, w1.z, a2); a3 = fmaf(xv.y, w1.w, a3);
        a0 = fmaf(xv.z, w2.x, a0); a1 = fmaf(xv.z, w2.y, a1); a2 = fmaf(xv.z, w2.z, a2); a3 = fmaf(xv.z, w2.w, a3);
        a0 = fmaf(xv.w, w3.x, a0); a1 = fmaf(xv.w, w3.y, a1); a2 = fmaf(xv.w, w3.z, a2); a3 = fmaf(xv.w, w3.w, a3);
    }
    for (int off = 32; off; off >>= 1) {
        a0 += __shfl_down(a0, off, 64);
        a1 += __shfl_down(a1, off, 64);
        a2 += __shfl_down(a2, off, 64);
        a3 += __shfl_down(a3, off, 64);
    }
    if (lane == 0)
        *reinterpret_cast<float4*>(h + (long long)row * 4) = make_float4(a0, a1, a2, a3);
}
__global__ __launch_bounds__(256) void k_deg_init(float* __restrict__ deg) {
    int i = blockIdx.x * blockDim.x + threadIdx.x;
    if (i < N_NODES) deg[i] = 1.0f;
}
__global__ __launch_bounds__(256) void k_dega(const int* __restrict__ ei,
                                              const float* __restrict__ ew,
                                              float* __restrict__ deg) {
    int e = blockIdx.x * blockDim.x + threadIdx.x;
    if (e < E_EDGES) atomicAdd(&deg[ei[E_EDGES + e]], ew[e]);
}
__global__ __launch_bounds__(256) void k_dinva(float* __restrict__ deg) {
    int i = blockIdx.x * blockDim.x + threadIdx.x;
    if (i < N_NODES) {
        float d = deg[i];
        deg[i] = (d > 0.f) ? (1.0f / sqrtf(d)) : 0.0f;
    }
}
__global__ __launch_bounds__(256) void k_selfa(const float* __restrict__ h,
                                               const float* __restrict__ dinv,
                                               const float* __restrict__ b,
                                               float* __restrict__ feat) {
    int i = blockIdx.x * blockDim.x + threadIdx.x;
    if (i < N_NODES) {
        float di = dinv[i];
        float s  = di * di;
        float4 hv = *reinterpret_cast<const float4*>(h + (long long)i * 4);
        float4 r;
        r.x = fmaf(s, hv.x, b[0]);
        r.y = fmaf(s, hv.y, b[1]);
        r.z = fmaf(s, hv.z, b[2]);
        r.w = fmaf(s, hv.w, b[3]);
        *reinterpret_cast<float4*>(feat + (long long)i * 4) = r;
    }
}
__global__ __launch_bounds__(256) void k_scattera(const int* __restrict__ ei,
                                                  const float* __restrict__ ew,
                                                  const float* __restrict__ dinv,
                                                  const float* __restrict__ h,
                                                  float* __restrict__ feat) {
    int e = blockIdx.x * blockDim.x + threadIdx.x;
    if (e >= E_EDGES) return;
    int s = ei[e];
    int d = ei[E_EDGES + e];
    float nrm = dinv[s] * ew[e] * dinv[d];
    float4 hv = *reinterpret_cast<const float4*>(h + (long long)s * 4);
    float* o = feat + (long long)d * 4;
    atomicAdd(o + 0, nrm * hv.x);
    atomicAdd(o + 1, nrm * hv.y);
    atomicAdd(o + 2, nrm * hv.z);
    atomicAdd(o + 3, nrm * hv.w);
}

extern "C" void kernel_launch(void* const* d_in, const int* in_sizes, int n_in,
                              void* d_out, int out_size, void* d_ws, size_t ws_size,
                              hipStream_t stream) {
    const float* x    = (const float*)d_in[0];
    const int*   ei   = (const int*)  d_in[1];
    const float* ea   = (const float*)d_in[2];
    const float* W    = (const float*)d_in[5];
    const float* b    = (const float*)d_in[6];
    const float* fc1w = (const float*)d_in[7];
    const float* fc1b = (const float*)d_in[8];
    const float* fc2w = (const float*)d_in[9];
    const float* fc2b = (const float*)d_in[10];
    float* out = (float*)d_out;

    char* ws = (char*)d_ws;
    // layout (bytes); feat overlays h (h dead after k_sort2)
    float*    h        = (float*)(ws);                    // 1,638,400
    float*    feat     = (float*)(ws);                    // overlay
    float*    dinv     = (float*)(ws + 1638400);          //   409,600
    float*    hs       = (float*)(ws + 2048000);          // 1,638,400
    unsigned* counts   = (unsigned*)(ws + 3686400);       // 1,638,400 (CNT*4)
    unsigned* bsum     = (unsigned*)(ws + 5324800);       //     1,600 (+pad)
    unsigned long long* sorted_a = (unsigned long long*)(ws + 5326848); // 52,428,800
    const size_t NEED = 5326848ull + 52428800ull;         // 57,755,648

    if (ws_size >= NEED) {
        // 1) fused: level-1 hist (blocks 0..GB-1) + xw
        int xw_blocks = (N_NODES + 3) / 4;
        k_xw_hist<<<GB + xw_blocks, 256, 0, stream>>>(x, W, ei, h, counts);
        // 2-3) scan of bucket counts
        k_scan1<<<SCANB, 256, 0, stream>>>(counts, bsum);
        k_scan2<<<1, 512, 0, stream>>>(bsum);
        // 4) level-1 reorder (single edge pass; hist from scanned-count diffs)
        k_binsort<<<GB, 1024, 0, stream>>>(ei, ea, counts, bsum, sorted_a);
        // 5) fixed-point weighted degree -> dinv, hs
        k_sort2<<<NBK, 1024, 0, stream>>>(counts, bsum, sorted_a, h, dinv, hs);
        // 6) gather (dl16+idx LDS, 2 blocks/CU)
        k_gather<<<NBK, 1024, 0, stream>>>(counts, bsum, sorted_a, hs, dinv, b, feat);
        // 7) MLP head
        k_mlp<<<B_GR, 256, 0, stream>>>(feat, fc1w, fc1b, fc2w, fc2b, out);
    } else {
        // fallback: global-atomic path
        float* hf   = (float*)(ws);
        float* ft   = (float*)(ws + 1638400);
        float* deg  = (float*)(ws + 3276800);
        k_xwf<<<(N_NODES + 3) / 4, 256, 0, stream>>>(x, W, hf);
        k_deg_init<<<(N_NODES + 255) / 256, 256, 0, stream>>>(deg);
        k_dega<<<(E_EDGES + 255) / 256, 256, 0, stream>>>(ei, ea, deg);
        k_dinva<<<(N_NODES + 255) / 256, 256, 0, stream>>>(deg);
        k_selfa<<<(N_NODES + 255) / 256, 256, 0, stream>>>(hf, deg, b, ft);
        k_scattera<<<(E_EDGES + 255) / 256, 256, 0, stream>>>(ei, ea, deg, hf, ft);
        k_mlp<<<B_GR, 256, 0, stream>>>(ft, fc1w, fc1b, fc2w, fc2b, out);
    }
}

// Round 10
// 169.337 us; speedup vs baseline: 1.1227x; 1.1227x over previous
//
#include <hip/hip_runtime.h>

constexpr int   N_NODES = 102400;      // B * NODES_PER_GRAPH
constexpr int   F_IN    = 400;
constexpr int   HIDF    = 4;
constexpr int   B_GR    = 256;
constexpr int   NPG     = 400;         // nodes per graph
constexpr int   E_EDGES = 6553600;

// two-level sort parameters
constexpr int   NBK     = 512;                 // buckets (dst/200)
constexpr int   NPB2    = 200;                 // nodes per bucket
constexpr int   GB      = 800;                 // binning blocks
constexpr int   CHUNK   = E_EDGES / GB;        // 8192 edges per block
constexpr int   HITERS  = CHUNK / 256;         // 32 (hist part of k_xw_hist)
constexpr int   CNT     = NBK * GB;            // 409600 counters
constexpr int   SCANB   = CNT / 1024;          // 400 scan blocks
constexpr int   CAP2    = 14336;               // bucket staging (mean 12800, +13 sigma)
constexpr float FPSCALE = 16777216.0f;         // 2^24 fixed-point for degree

// ---------------- fused: hist blocks first, then xw (independent) ----------------
__global__ __launch_bounds__(256) void k_xw_hist(const float* __restrict__ x,
                                                 const float* __restrict__ W,
                                                 const int* __restrict__ ei,
                                                 float* __restrict__ h,
                                                 unsigned* __restrict__ counts) {
    if (blockIdx.x < GB) {
        __shared__ unsigned hist[NBK];
        for (int i = threadIdx.x; i < NBK; i += 256) hist[i] = 0;
        __syncthreads();
        long long base = (long long)blockIdx.x * CHUNK;
        #pragma unroll 4
        for (int i = 0; i < HITERS; ++i) {
            int d = ei[E_EDGES + base + i * 256 + threadIdx.x];
            atomicAdd(&hist[d / NPB2], 1u);
        }
        __syncthreads();
        for (int i = threadIdx.x; i < NBK; i += 256)
            counts[(unsigned)i * GB + blockIdx.x] = hist[i];
        return;
    }
    int gtid = (blockIdx.x - GB) * 256 + threadIdx.x;
    int row  = gtid >> 6;
    int lane = threadIdx.x & 63;
    if (row >= N_NODES) return;
    const float* xr = x + (long long)row * F_IN;
    float a0 = 0.f, a1 = 0.f, a2 = 0.f, a3 = 0.f;
    for (int k0 = lane * 4; k0 < F_IN; k0 += 256) {
        float4 xv = *reinterpret_cast<const float4*>(xr + k0);
        float4 w0 = *reinterpret_cast<const float4*>(W + (k0 + 0) * 4);
        float4 w1 = *reinterpret_cast<const float4*>(W + (k0 + 1) * 4);
        float4 w2 = *reinterpret_cast<const float4*>(W + (k0 + 2) * 4);
        float4 w3 = *reinterpret_cast<const float4*>(W + (k0 + 3) * 4);
        a0 = fmaf(xv.x, w0.x, a0); a1 = fmaf(xv.x, w0.y, a1); a2 = fmaf(xv.x, w0.z, a2); a3 = fmaf(xv.x, w0.w, a3);
        a0 = fmaf(xv.y, w1.x, a0); a1 = fmaf(xv.y, w1.y, a1); a2 = fmaf(xv.y, w1.z, a2); a3 = fmaf(xv.y, w1.w, a3);
        a0 = fmaf(xv.z, w2.x, a0); a1 = fmaf(xv.z, w2.y, a1); a2 = fmaf(xv.z, w2.z, a2); a3 = fmaf(xv.z, w2.w, a3);
        a0 = fmaf(xv.w, w3.x, a0); a1 = fmaf(xv.w, w3.y, a1); a2 = fmaf(xv.w, w3.z, a2); a3 = fmaf(xv.w, w3.w, a3);
    }
    for (int off = 32; off; off >>= 1) {
        a0 += __shfl_down(a0, off, 64);
        a1 += __shfl_down(a1, off, 64);
        a2 += __shfl_down(a2, off, 64);
        a3 += __shfl_down(a3, off, 64);
    }
    if (lane == 0) {
        float4 r = make_float4(a0, a1, a2, a3);
        *reinterpret_cast<float4*>(h + (long long)row * 4) = r;
    }
}

// ---------------- scan1: per-1024-chunk exclusive scan ----------------
__global__ __launch_bounds__(256) void k_scan1(unsigned* __restrict__ data,
                                               unsigned* __restrict__ bsum) {
    __shared__ unsigned ts[256];
    int base = blockIdx.x * 1024 + threadIdx.x * 4;
    unsigned v0 = data[base], v1 = data[base + 1], v2 = data[base + 2], v3 = data[base + 3];
    unsigned s = v0 + v1 + v2 + v3;
    ts[threadIdx.x] = s;
    __syncthreads();
    for (int off = 1; off < 256; off <<= 1) {
        unsigned t = (threadIdx.x >= off) ? ts[threadIdx.x - off] : 0u;
        __syncthreads();
        ts[threadIdx.x] += t;
        __syncthreads();
    }
    unsigned excl = ts[threadIdx.x] - s;
    data[base]     = excl;
    data[base + 1] = excl + v0;
    data[base + 2] = excl + v0 + v1;
    data[base + 3] = excl + v0 + v1 + v2;
    if (threadIdx.x == 255) bsum[blockIdx.x] = ts[255];
}

// ---------------- scan2: exclusive scan of the SCANB chunk sums ----------------
__global__ __launch_bounds__(512) void k_scan2(unsigned* __restrict__ bsum) {
    __shared__ unsigned ts[512];
    int tid = threadIdx.x;
    unsigned v = (tid < SCANB) ? bsum[tid] : 0u;
    ts[tid] = v;
    __syncthreads();
    for (int off = 1; off < 512; off <<= 1) {
        unsigned t = (tid >= off) ? ts[tid - off] : 0u;
        __syncthreads();
        ts[tid] += t;
        __syncthreads();
    }
    if (tid < SCANB) bsum[tid] = ts[tid] - v;   // exclusive
}

// helper: global exclusive prefix at flat index (after scan1+scan2)
__device__ __forceinline__ unsigned pfx(const unsigned* counts, const unsigned* bsum,
                                        unsigned flat) {
    return (flat < (unsigned)CNT) ? (counts[flat] + bsum[flat >> 10]) : (unsigned)E_EDGES;
}

// ---------------- binsort v5: single pass, paired-edge loads ----------------
__global__ __launch_bounds__(1024) void k_binsort(const int* __restrict__ ei,
                                                  const float* __restrict__ ew,
                                                  const unsigned* __restrict__ counts,
                                                  const unsigned* __restrict__ bsum,
                                                  unsigned long long* __restrict__ sorted) {
    __shared__ unsigned long long st2[CHUNK];   // 64 KB, bucket-ordered staging
    __shared__ unsigned hist[NBK], lrank[NBK], lobase[NBK], obaseG[NBK];
    __shared__ unsigned wsum[8];
    int tid = threadIdx.x;
    unsigned v = 0, inc = 0;
    if (tid < NBK) {
        unsigned flat = (unsigned)tid * GB + blockIdx.x;
        unsigned o0 = pfx(counts, bsum, flat);
        unsigned o1 = pfx(counts, bsum, flat + 1);
        obaseG[tid] = o0;
        v = o1 - o0;                // this block's count for this bucket
        hist[tid] = v;
        lrank[tid] = 0;
        inc = v;
        #pragma unroll
        for (int d = 1; d < 64; d <<= 1) {
            unsigned t = __shfl_up(inc, d, 64);
            if ((tid & 63) >= d) inc += t;
        }
        if ((tid & 63) == 63) wsum[tid >> 6] = inc;
    }
    __syncthreads();
    if (tid < 8) {
        unsigned s = wsum[tid], si = s;
        #pragma unroll
        for (int d = 1; d < 8; d <<= 1) {
            unsigned t = __shfl_up(si, d, 64);
            if (tid >= d) si += t;
        }
        wsum[tid] = si - s;
    }
    __syncthreads();
    if (tid < NBK) lobase[tid] = inc - v + wsum[tid >> 6];
    __syncthreads();
    // single pass: paired-edge loads, permute into st2 (bucket-ordered in LDS)
    long long base = (long long)blockIdx.x * CHUNK;
    #pragma unroll
    for (int k = 0; k < CHUNK / 2048; ++k) {
        long long e0 = base + k * 2048 + 2 * tid;
        int2   sv = *reinterpret_cast<const int2*>(ei + e0);
        int2   dv = *reinterpret_cast<const int2*>(ei + E_EDGES + e0);
        float2 wv = *reinterpret_cast<const float2*>(ew + e0);
        {
            int bin  = dv.x / NPB2;
            int dloc = dv.x - bin * NPB2;
            unsigned r = atomicAdd(&lrank[bin], 1u);
            st2[lobase[bin] + r] = ((unsigned long long)__float_as_uint(wv.x) << 32)
                                 | ((unsigned)sv.x << 9) | (unsigned)dloc;
        }
        {
            int bin  = dv.y / NPB2;
            int dloc = dv.y - bin * NPB2;
            unsigned r = atomicAdd(&lrank[bin], 1u);
            st2[lobase[bin] + r] = ((unsigned long long)__float_as_uint(wv.y) << 32)
                                 | ((unsigned)sv.y << 9) | (unsigned)dloc;
        }
    }
    __syncthreads();
    // run write-out, 16-lane subgroup per bucket
    int sg = tid >> 4, l = tid & 15;
    for (int bin = sg; bin < NBK; bin += 64) {
        unsigned cnt = hist[bin];
        unsigned gb  = obaseG[bin];
        unsigned lb  = lobase[bin];
        for (unsigned k = l; k < cnt; k += 16)
            sorted[gb + k] = st2[lb + k];
    }
}

// ---------------- sort2 v4: fixed-point weighted degree -> dinv, hs ----------------
__global__ __launch_bounds__(1024) void k_sort2(const unsigned* __restrict__ counts,
                                                const unsigned* __restrict__ bsum,
                                                const unsigned long long* __restrict__ sa,
                                                const float* __restrict__ h,
                                                float* __restrict__ dinv,
                                                float* __restrict__ hs) {
    __shared__ unsigned dgu[NPB2];
    int tid = threadIdx.x;
    int b = blockIdx.x;
    unsigned s0 = pfx(counts, bsum, (unsigned)b * GB);
    unsigned s1 = pfx(counts, bsum, (unsigned)(b + 1) * GB);
    unsigned len = s1 - s0;
    if (tid < NPB2) dgu[tid] = 0;
    __syncthreads();
    unsigned i = tid;
    for (; i + 3 * 1024 < len; i += 4 * 1024) {
        unsigned long long p0 = sa[s0 + i];
        unsigned long long p1 = sa[s0 + i + 1024];
        unsigned long long p2 = sa[s0 + i + 2048];
        unsigned long long p3 = sa[s0 + i + 3072];
        atomicAdd(&dgu[(unsigned)p0 & 511u], __float2uint_rn(__uint_as_float((unsigned)(p0 >> 32)) * FPSCALE));
        atomicAdd(&dgu[(unsigned)p1 & 511u], __float2uint_rn(__uint_as_float((unsigned)(p1 >> 32)) * FPSCALE));
        atomicAdd(&dgu[(unsigned)p2 & 511u], __float2uint_rn(__uint_as_float((unsigned)(p2 >> 32)) * FPSCALE));
        atomicAdd(&dgu[(unsigned)p3 & 511u], __float2uint_rn(__uint_as_float((unsigned)(p3 >> 32)) * FPSCALE));
    }
    for (; i < len; i += 1024) {
        unsigned long long pk = sa[s0 + i];
        atomicAdd(&dgu[(unsigned)pk & 511u], __float2uint_rn(__uint_as_float((unsigned)(pk >> 32)) * FPSCALE));
    }
    __syncthreads();
    if (tid < NPB2 * 4) {
        int node = tid >> 2, c = tid & 3;
        float deg = 1.0f + (float)dgu[node] * (1.0f / FPSCALE);   // self-loop weight 1
        float di = rsqrtf(deg);
        int gnode = b * NPB2 + node;
        if (c == 0) dinv[gnode] = di;
        hs[gnode * 4 + c] = di * h[gnode * 4 + c];
    }
}

// ---------------- gather v4 (R8, proven): stage + idx, accumulate from LDS ----------------
__global__ __launch_bounds__(1024) void k_gather(const unsigned* __restrict__ counts,
                                                 const unsigned* __restrict__ bsum,
                                                 const unsigned long long* __restrict__ sa,
                                                 const float* __restrict__ hs,
                                                 const float* __restrict__ dinv,
                                                 const float* __restrict__ bias,
                                                 float* __restrict__ feat) {
    __shared__ unsigned long long st[CAP2];     // 114,688 B
    __shared__ unsigned short    idx[CAP2];     //  28,672 B
    __shared__ unsigned hist[NPB2], rnk[NPB2], obase[NPB2];
    __shared__ unsigned wsum[4];
    __shared__ float accf[4 * NPB2];            // overflow fallback only
    int tid = threadIdx.x;
    int b = blockIdx.x;
    unsigned s0 = pfx(counts, bsum, (unsigned)b * GB);
    unsigned s1 = pfx(counts, bsum, (unsigned)(b + 1) * GB);
    unsigned len = s1 - s0;
    bool staged = (len <= (unsigned)CAP2);
    if (tid < NPB2) { hist[tid] = 0; rnk[tid] = 0; }
    __syncthreads();
    if (staged) {
        for (unsigned i = tid; i < len; i += 1024) {
            unsigned long long pk = sa[s0 + i];
            st[i] = pk;
            atomicAdd(&hist[(unsigned)pk & 511u], 1u);
        }
        __syncthreads();
        unsigned v = 0, inc = 0;
        if (tid < 256) {
            v = (tid < NPB2) ? hist[tid] : 0u;
            inc = v;
            #pragma unroll
            for (int d = 1; d < 64; d <<= 1) {
                unsigned t = __shfl_up(inc, d, 64);
                if ((tid & 63) >= d) inc += t;
            }
            if ((tid & 63) == 63) wsum[tid >> 6] = inc;
        }
        __syncthreads();
        if (tid < 4) {
            unsigned s = wsum[tid], si = s;
            #pragma unroll
            for (int d = 1; d < 4; d <<= 1) {
                unsigned t = __shfl_up(si, d, 64);
                if (tid >= d) si += t;
            }
            wsum[tid] = si - s;
        }
        __syncthreads();
        if (tid < NPB2) obase[tid] = inc - v + wsum[tid >> 6];
        __syncthreads();
        for (unsigned i = tid; i < len; i += 1024) {
            unsigned dl = (unsigned)st[i] & 511u;
            unsigned r = atomicAdd(&rnk[dl], 1u);
            idx[obase[dl] + r] = (unsigned short)i;
        }
        __syncthreads();
        // per-node accumulate: 4 lanes/node, lane = component
        if (tid < NPB2 * 4) {
            int node = tid >> 2, c = tid & 3;
            unsigned jst = obase[node];
            unsigned jen = (node < NPB2 - 1) ? obase[node + 1] : len;
            float acc = 0.f;
            unsigned j = jst;
            for (; j + 4 <= jen; j += 4) {
                unsigned long long p0 = st[idx[j]];
                unsigned long long p1 = st[idx[j + 1]];
                unsigned long long p2 = st[idx[j + 2]];
                unsigned long long p3 = st[idx[j + 3]];
                float h0 = hs[(((unsigned)p0 >> 9) << 2) + c];
                float h1 = hs[(((unsigned)p1 >> 9) << 2) + c];
                float h2 = hs[(((unsigned)p2 >> 9) << 2) + c];
                float h3 = hs[(((unsigned)p3 >> 9) << 2) + c];
                acc = fmaf(__uint_as_float((unsigned)(p0 >> 32)), h0, acc);
                acc = fmaf(__uint_as_float((unsigned)(p1 >> 32)), h1, acc);
                acc = fmaf(__uint_as_float((unsigned)(p2 >> 32)), h2, acc);
                acc = fmaf(__uint_as_float((unsigned)(p3 >> 32)), h3, acc);
            }
            for (; j < jen; ++j) {
                unsigned long long pk = st[idx[j]];
                acc = fmaf(__uint_as_float((unsigned)(pk >> 32)),
                           hs[(((unsigned)pk >> 9) << 2) + c], acc);
            }
            int gnode = b * NPB2 + node;
            feat[gnode * 4 + c] = fmaf(dinv[gnode], acc + hs[gnode * 4 + c], bias[c]);
        }
    } else {
        // overflow fallback (statistically never): f32 LDS atomics
        for (int i = tid; i < 4 * NPB2; i += 1024) accf[i] = 0.f;
        __syncthreads();
        for (unsigned i = tid; i < len; i += 1024) {
            unsigned long long pk = sa[s0 + i];
            unsigned lo = (unsigned)pk;
            float w = __uint_as_float((unsigned)(pk >> 32));
            int dl = lo & 511;
            const float* hv = hs + (((unsigned)lo >> 9) << 2);
            atomicAdd(&accf[dl * 4 + 0], w * hv[0]);
            atomicAdd(&accf[dl * 4 + 1], w * hv[1]);
            atomicAdd(&accf[dl * 4 + 2], w * hv[2]);
            atomicAdd(&accf[dl * 4 + 3], w * hv[3]);
        }
        __syncthreads();
        if (tid < NPB2 * 4) {
            int node = tid >> 2, c = tid & 3;
            int gnode = b * NPB2 + node;
            feat[gnode * 4 + c] = fmaf(dinv[gnode], accf[node * 4 + c] + hs[gnode * 4 + c], bias[c]);
        }
    }
}

// ---------------- mlp: per-graph FC head ----------------
__global__ __launch_bounds__(256) void k_mlp(const float* __restrict__ feat,
                                             const float* __restrict__ fc1w,
                                             const float* __restrict__ fc1b,
                                             const float* __restrict__ fc2w,
                                             const float* __restrict__ fc2b,
                                             float* __restrict__ out) {
    __shared__ float row[NPG * HIDF];
    __shared__ float part[8][32];
    __shared__ float h1[32];
    int g = blockIdx.x;
    const float* fr = feat + (long long)g * (NPG * HIDF);
    for (int i = threadIdx.x; i < NPG * HIDF; i += 256) row[i] = fr[i];
    __syncthreads();
    int j = threadIdx.x & 31;
    int c8 = threadIdx.x >> 5;
    float acc = 0.f;
    int k0 = c8 * 200, k1 = k0 + 200;
    for (int k = k0; k < k1; ++k) acc = fmaf(row[k], fc1w[k * 32 + j], acc);
    part[c8][j] = acc;
    __syncthreads();
    if (threadIdx.x < 32) {
        float s = fc1b[j];
        #pragma unroll
        for (int cc = 0; cc < 8; ++cc) s += part[cc][j];
        h1[j] = fmaxf(s, 0.f);
    }
    __syncthreads();
    if (threadIdx.x < 2) {
        float s = fc2b[threadIdx.x];
        #pragma unroll
        for (int k = 0; k < 32; ++k) s = fmaf(h1[k], fc2w[k * 2 + threadIdx.x], s);
        out[g * 2 + threadIdx.x] = s;
    }
    if (g == 0 && threadIdx.x == 0) out[B_GR * 2] = 0.0f;
}

// ---------------- fallback path (global atomics, ~5.3 MB ws) ----------------
__global__ __launch_bounds__(256) void k_xwf(const float* __restrict__ x,
                                             const float* __restrict__ W,
                                             float* __restrict__ h) {
    int gtid = blockIdx.x * 256 + threadIdx.x;
    int row  = gtid >> 6;
    int lane = threadIdx.x & 63;
    if (row >= N_NODES) return;
    const float* xr = x + (long long)row * F_IN;
    float a0 = 0.f, a1 = 0.f, a2 = 0.f, a3 = 0.f;
    for (int k0 = lane * 4; k0 < F_IN; k0 += 256) {
        float4 xv = *reinterpret_cast<const float4*>(xr + k0);
        float4 w0 = *reinterpret_cast<const float4*>(W + (k0 + 0) * 4);
        float4 w1 = *reinterpret_cast<const float4*>(W + (k0 + 1) * 4);
        float4 w2 = *reinterpret_cast<const float4*>(W + (k0 + 2) * 4);
        float4 w3 = *reinterpret_cast<const float4*>(W + (k0 + 3) * 4);
        a0 = fmaf(xv.x, w0.x, a0); a1 = fmaf(xv.x, w0.y, a1); a2 = fmaf(xv.x, w0.z, a2); a3 = fmaf(xv.x, w0.w, a3);
        a0 = fmaf(xv.y, w1.x, a0); a1 = fmaf(xv.y, w1.y, a1); a2 = fmaf(xv.y, w1.z, a2); a3 = fmaf(xv.y, w1.w, a3);
        a0 = fmaf(xv.z, w2.x, a0); a1 = fmaf(xv.z, w2.y, a1); a2 = fmaf(xv.z, w2.z, a2); a3 = fmaf(xv.z, w2.w, a3);
        a0 = fmaf(xv.w, w3.x, a0); a1 = fmaf(xv.w, w3.y, a1); a2 = fmaf(xv.w, w3.z, a2); a3 = fmaf(xv.w, w3.w, a3);
    }
    for (int off = 32; off; off >>= 1) {
        a0 += __shfl_down(a0, off, 64);
        a1 += __shfl_down(a1, off, 64);
        a2 += __shfl_down(a2, off, 64);
        a3 += __shfl_down(a3, off, 64);
    }
    if (lane == 0)
        *reinterpret_cast<float4*>(h + (long long)row * 4) = make_float4(a0, a1, a2, a3);
}
__global__ __launch_bounds__(256) void k_deg_init(float* __restrict__ deg) {
    int i = blockIdx.x * blockDim.x + threadIdx.x;
    if (i < N_NODES) deg[i] = 1.0f;
}
__global__ __launch_bounds__(256) void k_dega(const int* __restrict__ ei,
                                              const float* __restrict__ ew,
                                              float* __restrict__ deg) {
    int e = blockIdx.x * blockDim.x + threadIdx.x;
    if (e < E_EDGES) atomicAdd(&deg[ei[E_EDGES + e]], ew[e]);
}
__global__ __launch_bounds__(256) void k_dinva(float* __restrict__ deg) {
    int i = blockIdx.x * blockDim.x + threadIdx.x;
    if (i < N_NODES) {
        float d = deg[i];
        deg[i] = (d > 0.f) ? (1.0f / sqrtf(d)) : 0.0f;
    }
}
__global__ __launch_bounds__(256) void k_selfa(const float* __restrict__ h,
                                               const float* __restrict__ dinv,
                                               const float* __restrict__ b,
                                               float* __restrict__ feat) {
    int i = blockIdx.x * blockDim.x + threadIdx.x;
    if (i < N_NODES) {
        float di = dinv[i];
        float s  = di * di;
        float4 hv = *reinterpret_cast<const float4*>(h + (long long)i * 4);
        float4 r;
        r.x = fmaf(s, hv.x, b[0]);
        r.y = fmaf(s, hv.y, b[1]);
        r.z = fmaf(s, hv.z, b[2]);
        r.w = fmaf(s, hv.w, b[3]);
        *reinterpret_cast<float4*>(feat + (long long)i * 4) = r;
    }
}
__global__ __launch_bounds__(256) void k_scattera(const int* __restrict__ ei,
                                                  const float* __restrict__ ew,
                                                  const float* __restrict__ dinv,
                                                  const float* __restrict__ h,
                                                  float* __restrict__ feat) {
    int e = blockIdx.x * blockDim.x + threadIdx.x;
    if (e >= E_EDGES) return;
    int s = ei[e];
    int d = ei[E_EDGES + e];
    float nrm = dinv[s] * ew[e] * dinv[d];
    float4 hv = *reinterpret_cast<const float4*>(h + (long long)s * 4);
    float* o = feat + (long long)d * 4;
    atomicAdd(o + 0, nrm * hv.x);
    atomicAdd(o + 1, nrm * hv.y);
    atomicAdd(o + 2, nrm * hv.z);
    atomicAdd(o + 3, nrm * hv.w);
}

extern "C" void kernel_launch(void* const* d_in, const int* in_sizes, int n_in,
                              void* d_out, int out_size, void* d_ws, size_t ws_size,
                              hipStream_t stream) {
    const float* x    = (const float*)d_in[0];
    const int*   ei   = (const int*)  d_in[1];
    const float* ea   = (const float*)d_in[2];
    const float* W    = (const float*)d_in[5];
    const float* b    = (const float*)d_in[6];
    const float* fc1w = (const float*)d_in[7];
    const float* fc1b = (const float*)d_in[8];
    const float* fc2w = (const float*)d_in[9];
    const float* fc2b = (const float*)d_in[10];
    float* out = (float*)d_out;

    char* ws = (char*)d_ws;
    // layout (bytes); feat overlays h (h dead after k_sort2)
    float*    h        = (float*)(ws);                    // 1,638,400
    float*    feat     = (float*)(ws);                    // overlay
    float*    dinv     = (float*)(ws + 1638400);          //   409,600
    float*    hs       = (float*)(ws + 2048000);          // 1,638,400
    unsigned* counts   = (unsigned*)(ws + 3686400);       // 1,638,400 (CNT*4)
    unsigned* bsum     = (unsigned*)(ws + 5324800);       //     1,600 (+pad)
    unsigned long long* sorted_a = (unsigned long long*)(ws + 5326848); // 52,428,800
    const size_t NEED = 5326848ull + 52428800ull;         // 57,755,648

    if (ws_size >= NEED) {
        // 1) fused: level-1 hist (blocks 0..GB-1) + xw
        int xw_blocks = (N_NODES + 3) / 4;
        k_xw_hist<<<GB + xw_blocks, 256, 0, stream>>>(x, W, ei, h, counts);
        // 2-3) scan of bucket counts
        k_scan1<<<SCANB, 256, 0, stream>>>(counts, bsum);
        k_scan2<<<1, 512, 0, stream>>>(bsum);
        // 4) level-1 reorder (paired-edge loads)
        k_binsort<<<GB, 1024, 0, stream>>>(ei, ea, counts, bsum, sorted_a);
        // 5) fixed-point weighted degree -> dinv, hs
        k_sort2<<<NBK, 1024, 0, stream>>>(counts, bsum, sorted_a, h, dinv, hs);
        // 6) gather (LDS-staged edge records, R8-proven)
        k_gather<<<NBK, 1024, 0, stream>>>(counts, bsum, sorted_a, hs, dinv, b, feat);
        // 7) MLP head
        k_mlp<<<B_GR, 256, 0, stream>>>(feat, fc1w, fc1b, fc2w, fc2b, out);
    } else {
        // fallback: global-atomic path
        float* hf   = (float*)(ws);
        float* ft   = (float*)(ws + 1638400);
        float* deg  = (float*)(ws + 3276800);
        k_xwf<<<(N_NODES + 3) / 4, 256, 0, stream>>>(x, W, hf);
        k_deg_init<<<(N_NODES + 255) / 256, 256, 0, stream>>>(deg);
        k_dega<<<(E_EDGES + 255) / 256, 256, 0, stream>>>(ei, ea, deg);
        k_dinva<<<(N_NODES + 255) / 256, 256, 0, stream>>>(deg);
        k_selfa<<<(N_NODES + 255) / 256, 256, 0, stream>>>(hf, deg, b, ft);
        k_scattera<<<(E_EDGES + 255) / 256, 256, 0, stream>>>(ei, ea, deg, hf, ft);
        k_mlp<<<B_GR, 256, 0, stream>>>(ft, fc1w, fc1b, fc2w, fc2b, out);
    }
}